// Round 13
// baseline (238.844 us; speedup 1.0000x reference)
//
#include <hip/hip_runtime.h>
#include <hip/hip_bf16.h>

// N=500000, D=64, K=512 (fp32 in/out).
// out rows: [0,K)=xw_sum, [K,2K)=w_sum, row 2K = inertia broadcast to 64 cols.

#define D_DIM 64
#define K_CLUS 512
#define RPT 128           // X rows per tile in assign
#define AGRID_MAX 1024    // assign grid (4 blocks/CU)
#define SEGROWS 64        // rows per accumulation segment (balanced)

typedef __attribute__((ext_vector_type(8))) short short8;
typedef __attribute__((ext_vector_type(4))) float f32x4;

// LDS-only barrier (no vmcnt drain; stores/prefetch stay in flight)
__device__ inline void barrier_lds_only() {
    asm volatile("s_waitcnt lgkmcnt(0)\n\ts_barrier" ::: "memory");
}

__device__ inline float dot4sq(float4 a) {
    return a.x * a.x + a.y * a.y + a.z * a.z + a.w * a.w;
}
__device__ inline unsigned short bfb(float f) {   // fp32 -> bf16 bits, RNE
    unsigned int u = __float_as_uint(f);
    return (unsigned short)((u + 0x7FFFu + ((u >> 16) & 1u)) >> 16);
}
__device__ inline short8 pack8f(float4 a, float4 b) {
    union { short8 s; __hip_bfloat162 q[4]; } r;
    r.q[0] = __float22bfloat162_rn(make_float2(a.x, a.y));
    r.q[1] = __float22bfloat162_rn(make_float2(a.z, a.w));
    r.q[2] = __float22bfloat162_rn(make_float2(b.x, b.y));
    r.q[3] = __float22bfloat162_rn(make_float2(b.z, b.w));
    return r.s;
}
__device__ inline float bfhi(unsigned u) { return __uint_as_float(u & 0xFFFF0000u); }
__device__ inline float bflo(unsigned u) { return __uint_as_float(u << 16); }

// -------- Kernel 1: cc + bf16 pack of C + (fused) zero ws page & d_out --------
// grid = 6 x 256: blocks 0,1 = cc; block 2 = zero ws[0..4096); blocks 3..5 = zero out.
__global__ __launch_bounds__(256) void cc_kernel(
        const float* __restrict__ C, float* __restrict__ CChalf,
        unsigned short* __restrict__ Cb, int k_total,
        int* __restrict__ wspage, float* __restrict__ out, int out_sz) {
    int b = blockIdx.x, tid = threadIdx.x;
    if (b < 2) {
        int k = b * 256 + tid;
        if (k >= k_total) return;
        const float4* cp = (const float4*)(C + (size_t)k * D_DIM);
        unsigned short* ob = Cb + (size_t)k * D_DIM;
        float s = 0.f;
#pragma unroll
        for (int i = 0; i < 16; ++i) {
            float4 c = cp[i];
            s += dot4sq(c);
            ob[4 * i + 0] = bfb(c.x); ob[4 * i + 1] = bfb(c.y);
            ob[4 * i + 2] = bfb(c.z); ob[4 * i + 3] = bfb(c.w);
        }
        CChalf[k] = 0.5f * s;
    } else if (b == 2) {
        int4 z = {0, 0, 0, 0};
        ((int4*)wspage)[tid] = z;                 // 256 x 16B = 4096B
    } else {
        float4 z = {0.f, 0.f, 0.f, 0.f};
        float4* o4 = (float4*)out;
        int n4 = out_sz >> 2;
        for (int i = (b - 3) * 256 + tid; i < n4; i += 768) o4[i] = z;
    }
}

// ---------------- Kernel 2: MFMA assignment, work-stealing tiles ----------------
// Wave w owns clusters [w*64,(w+1)*64) as MFMA A-frags in registers; X tiles
// (128 rows bf16, XOR-swizzled) staged in LDS; chained-acc MFMA. Tiles are
// pulled from a global counter (2-ahead id prefetch), so tail/ramp/CU skew
// disappears; merge is distributed across all 8 waves (lanes 0-15 each).
__global__ __launch_bounds__(512, 4) void assign_mfma(
        const float* __restrict__ X, const unsigned short* __restrict__ Cb,
        const float* __restrict__ CChalf, int* __restrict__ y,
        int* __restrict__ lrank, int* __restrict__ baseTab,
        int* __restrict__ count, float* __restrict__ inertia_ws,
        uint4* __restrict__ X16, int* __restrict__ workctr,
        int* __restrict__ tileOwner, int n, int ntiles) {
    __shared__ __align__(16) char xb_lds[RPT * 128];        // 16 KB bf16, swizzled
    __shared__ __align__(16) unsigned int partial[RPT][8];  // 4 KB keys
    __shared__ float xs_lds[2][RPT];                        // 1 KB ||x||^2, dbuf
    __shared__ int lhist[K_CLUS];                           // 2 KB local histogram
    __shared__ int idq[4];                                  // tile-id queue

    int tid = threadIdx.x;
    lhist[tid] = 0;
    if (tid == 0) {
        idq[0] = atomicAdd(workctr, 1);
        idq[1] = atomicAdd(workctr, 1);
    }

    int lane = tid & 63, wid = tid >> 6;
    int c15 = lane & 15, g = lane >> 4;
    int wbase = wid * 64;

    short8 cf0[4], cf1[4];
    f32x4 nc[4];                           // acc init = -0.5||c||^2 per reg slot
#pragma unroll
    for (int ct = 0; ct < 4; ++ct) {
        const char* cp = (const char*)(Cb + (size_t)(wbase + ct * 16 + c15) * D_DIM);
        cf0[ct] = *(const short8*)(cp + (g << 4));          // k = 8g..8g+7
        cf1[ct] = *(const short8*)(cp + 64 + (g << 4));     // k = 32+8g..
#pragma unroll
        for (int r2 = 0; r2 < 4; ++r2)
            nc[ct][r2] = -CChalf[wbase + ct * 16 + (g << 2) + r2];
    }

    // staging: thread covers 32B of row srow (A) and row 64+srow (B)
    int srow = tid >> 3;
    int sb = (tid & 7) << 4;
    int sf = (tid & 7) << 3;
    unsigned swz = ((unsigned)(srow & 7)) << 4;

    __syncthreads();                       // publish idq + lhist zeros
    int tile = idq[0], tnext = idq[1];

    float4 a0 = {0,0,0,0}, a1 = {0,0,0,0}, b0 = {0,0,0,0}, b1 = {0,0,0,0};
    if (tile < ntiles) {
        int rA = min(tile * RPT + srow, n - 1);
        int rB = min(tile * RPT + 64 + srow, n - 1);
        const float4* xa = (const float4*)(X + (size_t)rA * D_DIM + sf);
        const float4* xb = (const float4*)(X + (size_t)rB * D_DIM + sf);
        a0 = xa[0]; a1 = xa[1]; b0 = xb[0]; b1 = xb[1];
    }
    float iner = 0.f;
    int it = 0;

    while (tile < ntiles) {
        int par = it & 1;
        int rA = min(tile * RPT + srow, n - 1);
        int rB = min(tile * RPT + 64 + srow, n - 1);
        short8 pA = pack8f(a0, a1);
        short8 pB = pack8f(b0, b1);
        *(short8*)(xb_lds + (srow << 7) + (sb ^ swz)) = pA;
        *(short8*)(xb_lds + ((64 + srow) << 7) + (sb ^ swz)) = pB;
        float psA = dot4sq(a0) + dot4sq(a1);
        float psB = dot4sq(b0) + dot4sq(b1);
        psA += __shfl_xor(psA, 1); psA += __shfl_xor(psA, 2); psA += __shfl_xor(psA, 4);
        psB += __shfl_xor(psB, 1); psB += __shfl_xor(psB, 2); psB += __shfl_xor(psB, 4);
        if ((tid & 7) == 0) {
            xs_lds[par][srow] = psA;
            xs_lds[par][64 + srow] = psB;
        }
        barrier_lds_only();                                // stage visible

        // tile-id prefetch (2 ahead) + owner record: latency hides under sweep
        if (tid == 0) {
            tileOwner[tile] = blockIdx.x;
            idq[(it + 2) & 3] = atomicAdd(workctr, 1);
        }

        // X16 stores drain during the sweep
        union { short8 s8; uint4 u4; } cA, cB;
        cA.s8 = pA; cB.s8 = pB;
        X16[(size_t)rA * 8 + (tid & 7)] = cA.u4;
        X16[(size_t)rB * 8 + (tid & 7)] = cB.u4;

        // prefetch next tile's X rows
        if (tnext < ntiles) {
            int nA = min(tnext * RPT + srow, n - 1);
            int nB = min(tnext * RPT + 64 + srow, n - 1);
            const float4* xa = (const float4*)(X + (size_t)nA * D_DIM + sf);
            const float4* xb = (const float4*)(X + (size_t)nB * D_DIM + sf);
            a0 = xa[0]; a1 = xa[1]; b0 = xb[0]; b1 = xb[1];
        }

        // ---- sweep: 8 row-subtiles x wave's 64 clusters ----
#pragma unroll
        for (int s = 0; s < 8; ++s) {
            int arow = s * 16 + c15;
            const char* ab = xb_lds + (arow << 7);
            unsigned asw = ((unsigned)(arow & 7)) << 4;
            short8 xa = *(const short8*)(ab + ((g << 4) ^ asw));
            short8 xbv = *(const short8*)(ab + ((64 + (g << 4)) ^ asw));

            float best = -3.4e38f;
            int bpos = 0;
#pragma unroll
            for (int ct = 0; ct < 4; ++ct) {
                f32x4 acc = __builtin_amdgcn_mfma_f32_16x16x32_bf16(cf0[ct], xa, nc[ct], 0, 0, 0);
                acc = __builtin_amdgcn_mfma_f32_16x16x32_bf16(cf1[ct], xbv, acc, 0, 0, 0);
                float sc0 = acc[0], sc1 = acc[1], sc2 = acc[2], sc3 = acc[3];
                bool b01 = sc1 > sc0;  float v01 = b01 ? sc1 : sc0;  int p01 = b01 ? 1 : 0;
                bool b23 = sc3 > sc2;  float v23 = b23 ? sc3 : sc2;  int p23 = b23 ? 3 : 2;
                bool bq  = v23 > v01;  float vq  = bq ? v23 : v01;   int pq  = bq ? p23 : p01;
                if (vq > best) { best = vq; bpos = (ct << 2) + pq; }
            }
            int kg = wbase + ((bpos >> 2) << 4) + (g << 2) + (bpos & 3);
            unsigned u = __float_as_uint(best);
            unsigned mono = u ^ ((u & 0x80000000u) ? 0xFFFFFFFFu : 0x80000000u);
            unsigned key = (mono & 0xFFFFFE00u) | ((unsigned)kg ^ 0x1FFu);
            unsigned o = (unsigned)__shfl_xor((int)key, 16); key = key > o ? key : o;
            o = (unsigned)__shfl_xor((int)key, 32); key = key > o ? key : o;
            if (g == 0) partial[s * 16 + c15][wid] = key;
        }
        barrier_lds_only();                                // partials + idq visible

        // ---- merge: distributed, wave w handles rows [16w,16w+16) ----
        if ((lane >> 4) == 0) {
            int r = (wid << 4) + c15;
            int grow = tile * RPT + r;
            if (grow < n) {
                const uint4* pp = (const uint4*)&partial[r][0];
                uint4 p0 = pp[0], p1 = pp[1];
                unsigned key = p0.x;
                key = key > p0.y ? key : p0.y;
                key = key > p0.z ? key : p0.z;
                key = key > p0.w ? key : p0.w;
                key = key > p1.x ? key : p1.x;
                key = key > p1.y ? key : p1.y;
                key = key > p1.z ? key : p1.z;
                key = key > p1.w ? key : p1.w;
                int kg = (int)((key & 0x1FFu) ^ 0x1FFu);
                unsigned m2 = (key & 0xFFFFFE00u) | 0x100u;
                unsigned ub = (m2 & 0x80000000u) ? (m2 ^ 0x80000000u) : ~m2;
                float sbest = __uint_as_float(ub);
                float xx = xs_lds[par][r];
                y[grow] = kg;
                lrank[grow] = atomicAdd(&lhist[kg], 1);
                iner += sqrtf(fmaxf(xx - 2.f * sbest, 0.f) * (1.0f / 64.0f));
            }
        }
        tile = tnext;
        tnext = idq[(it + 2) & 3];
        ++it;
    }

    __syncthreads();                       // once: full sync before flush
    int b = atomicAdd(count + tid, lhist[tid]);
    baseTab[blockIdx.x * K_CLUS + tid] = b;

#pragma unroll
    for (int off = 1; off < 64; off <<= 1) iner += __shfl_xor(iner, off);
    if (lane == 0) atomicAdd(inertia_ws, iner);
}

// ------- Kernel 3: prefix sums + segment worklist + (fused) inertia row -------
__global__ __launch_bounds__(K_CLUS) void prefix_kernel(
        const int* __restrict__ count, int* __restrict__ offset,
        int* __restrict__ segKS, int* __restrict__ segmeta,
        const float* __restrict__ inertia_ws, float* __restrict__ out) {
    __shared__ int tmp[K_CLUS];
    __shared__ int tns[K_CLUS];
    int t = threadIdx.x;
    int c = count[t];
    int ns = (c + SEGROWS - 1) / SEGROWS;
    tmp[t] = c; tns[t] = ns;
    __syncthreads();
    for (int s = 1; s < K_CLUS; s <<= 1) {
        int v1 = (t >= s) ? tmp[t - s] : 0;
        int v2 = (t >= s) ? tns[t - s] : 0;
        __syncthreads();
        tmp[t] += v1; tns[t] += v2;
        __syncthreads();
    }
    offset[t] = tmp[t] - c;                 // exclusive row offset
    int so = tns[t] - ns;                   // exclusive segment offset
    for (int s = 0; s < ns; ++s) segKS[so + s] = (t << 16) | s;
    if (t == K_CLUS - 1) segmeta[0] = tns[t];
    if (t < D_DIM) out[(size_t)(2 * K_CLUS) * D_DIM + t] = *inertia_ws;  // finalize
}

// ---------------- Kernel 4: scatter rows into cluster-sorted order ----------------
__global__ __launch_bounds__(256) void scatter_kernel(
        const int* __restrict__ y, const int* __restrict__ lrank,
        const int* __restrict__ offset, const int* __restrict__ baseTab,
        const int* __restrict__ tileOwner, int* __restrict__ sorted, int n) {
    int row = blockIdx.x * blockDim.x + threadIdx.x;
    if (row >= n) return;
    int k = y[row];
    int blk = tileOwner[row >> 7];    // RPT=128 rows per tile; dynamic owner
    sorted[offset[k] + baseTab[blk * K_CLUS + k] + lrank[row]] = row;
}

// ------- Kernel 5: compressed gather accumulation -------
__global__ __launch_bounds__(256, 6) void cluster_accum_v3(
        const uint4* __restrict__ X16, const float* __restrict__ W,
        const int* __restrict__ sorted, const int* __restrict__ offset,
        const int* __restrict__ count, const int* __restrict__ segKS,
        const int* __restrict__ segmeta, float* __restrict__ out) {
    int bid = blockIdx.x;
    if (bid >= segmeta[0]) return;
    int v = segKS[bid];
    int k = v >> 16, s = v & 0xFFFF;
    int cnt = count[k];
    int lo = s * SEGROWS;
    int m = min(cnt - lo, SEGROWS);
    int start = offset[k] + lo;
    int lane = threadIdx.x & 63, w = threadIdx.x >> 6;
    int grp = (w << 2) | (lane >> 4);       // 0..15
    int l8 = lane & 7;
    int h = (lane >> 3) & 1;
    int g4 = grp * 4;
    const float4* W4 = (const float4*)W;

    int i0 = g4 + h;
    int i1 = g4 + 2 + h;
    int r0 = (i0 < m) ? sorted[start + i0] : -1;
    int r1 = (i1 < m) ? sorted[start + i1] : -1;

    uint4 zz = {0u, 0u, 0u, 0u};
    float4 fz = {0.f, 0.f, 0.f, 0.f};
    uint4 xq0 = zz, xq1 = zz;
    float4 wa0 = fz, wb0 = fz, wa1 = fz, wb1 = fz;
    if (r0 >= 0) {
        xq0 = X16[(size_t)r0 * 8 + l8];
        wa0 = W4[(size_t)r0 * 16 + 2 * l8];
        wb0 = W4[(size_t)r0 * 16 + 2 * l8 + 1];
    }
    if (r1 >= 0) {
        xq1 = X16[(size_t)r1 * 8 + l8];
        wa1 = W4[(size_t)r1 * 16 + 2 * l8];
        wb1 = W4[(size_t)r1 * 16 + 2 * l8 + 1];
    }

    float axw[8], aww[8];
#pragma unroll
    for (int j = 0; j < 8; ++j) { axw[j] = 0.f; aww[j] = 0.f; }

#pragma unroll
    for (int r = 0; r < 2; ++r) {
        uint4 xq = r ? xq1 : xq0;
        float4 wa = r ? wa1 : wa0;
        float4 wb = r ? wb1 : wb0;
        float xf[8];
        xf[0] = bflo(xq.x); xf[1] = bfhi(xq.x);
        xf[2] = bflo(xq.y); xf[3] = bfhi(xq.y);
        xf[4] = bflo(xq.z); xf[5] = bfhi(xq.z);
        xf[6] = bflo(xq.w); xf[7] = bfhi(xq.w);
        axw[0] = fmaf(xf[0], wa.x, axw[0]); aww[0] += wa.x;
        axw[1] = fmaf(xf[1], wa.y, axw[1]); aww[1] += wa.y;
        axw[2] = fmaf(xf[2], wa.z, axw[2]); aww[2] += wa.z;
        axw[3] = fmaf(xf[3], wa.w, axw[3]); aww[3] += wa.w;
        axw[4] = fmaf(xf[4], wb.x, axw[4]); aww[4] += wb.x;
        axw[5] = fmaf(xf[5], wb.y, axw[5]); aww[5] += wb.y;
        axw[6] = fmaf(xf[6], wb.z, axw[6]); aww[6] += wb.z;
        axw[7] = fmaf(xf[7], wb.w, axw[7]); aww[7] += wb.w;
    }
#pragma unroll
    for (int j = 0; j < 8; ++j) {
        axw[j] += __shfl_xor(axw[j], 8);
        aww[j] += __shfl_xor(aww[j], 8);
    }

    __shared__ float sxw[16][D_DIM];
    __shared__ float sww[16][D_DIM];
    if (h == 0) {
#pragma unroll
        for (int j = 0; j < 8; ++j) {
            sxw[grp][8 * l8 + j] = axw[j];
            sww[grp][8 * l8 + j] = aww[j];
        }
    }
    __syncthreads();
    int t = threadIdx.x;
    if (t < 128) {
        int half = t >> 6, d = t & 63;
        const float(*src)[D_DIM] = half ? sww : sxw;
        float acc = 0.f;
#pragma unroll
        for (int jg = 0; jg < 16; ++jg) acc += src[jg][d];
        atomicAdd(out + (size_t)(half ? K_CLUS + k : k) * D_DIM + d, acc);
    }
}

// ---------------- Fallback-only kernels ----------------
__global__ void finalize_kernel(const float* __restrict__ inertia_ws, float* __restrict__ out) {
    out[(size_t)(2 * K_CLUS) * D_DIM + threadIdx.x] = *inertia_ws;
}

__global__ __launch_bounds__(256) void assign_scalar(
        const float* __restrict__ X, const float* __restrict__ C,
        const float* __restrict__ CChalf, int* __restrict__ y,
        int* __restrict__ count, float* __restrict__ inertia_ws, int n) {
    int row = blockIdx.x * blockDim.x + threadIdx.x;
    float mind = 0.f;
    if (row < n) {
        float4 x[16];
        const float4* xp = (const float4*)(X + (size_t)row * D_DIM);
#pragma unroll
        for (int i = 0; i < 16; ++i) x[i] = xp[i];
        float xx = 0.f;
#pragma unroll
        for (int i = 0; i < 16; ++i) xx += dot4sq(x[i]);
        float best = -3.4e38f;
        int bestk = 0;
        for (int k = 0; k < K_CLUS; ++k) {
            const float4* cp = (const float4*)(C + (size_t)k * D_DIM);
            float s0 = 0.f;
#pragma unroll
            for (int i = 0; i < 16; ++i) {
                float4 c = cp[i];
                s0 += x[i].x * c.x + x[i].y * c.y + x[i].z * c.z + x[i].w * c.w;
            }
            float sc = s0 - CChalf[k];
            if (sc > best) { best = sc; bestk = k; }
        }
        y[row] = bestk;
        atomicAdd(&count[bestk], 1);
        mind = sqrtf(fmaxf(xx - 2.f * best, 0.f) * (1.0f / 64.0f));
    }
    float s = mind;
#pragma unroll
    for (int off = 32; off > 0; off >>= 1) s += __shfl_xor(s, off);
    __shared__ float wsum[4];
    int w = threadIdx.x >> 6;
    if ((threadIdx.x & 63) == 0) wsum[w] = s;
    __syncthreads();
    if (threadIdx.x == 0)
        atomicAdd(inertia_ws, wsum[0] + wsum[1] + wsum[2] + wsum[3]);
}

__global__ __launch_bounds__(256) void accum_atomic_kernel(
        const float* __restrict__ X, const float* __restrict__ W,
        const int* __restrict__ y, float* __restrict__ out, int n) {
    int row = blockIdx.x * blockDim.x + threadIdx.x;
    if (row >= n) return;
    int k = y[row];
    const float4* xp = (const float4*)(X + (size_t)row * D_DIM);
    const float4* wp = (const float4*)(W + (size_t)row * D_DIM);
    float* xw = out + (size_t)k * D_DIM;
    float* wsv = out + (size_t)(K_CLUS + k) * D_DIM;
#pragma unroll
    for (int i = 0; i < 16; ++i) {
        float4 x = xp[i];
        float4 wq = wp[i];
        atomicAdd(xw + 4 * i + 0, x.x * wq.x);
        atomicAdd(xw + 4 * i + 1, x.y * wq.y);
        atomicAdd(xw + 4 * i + 2, x.z * wq.z);
        atomicAdd(xw + 4 * i + 3, x.w * wq.w);
        atomicAdd(wsv + 4 * i + 0, wq.x);
        atomicAdd(wsv + 4 * i + 1, wq.y);
        atomicAdd(wsv + 4 * i + 2, wq.z);
        atomicAdd(wsv + 4 * i + 3, wq.w);
    }
}

extern "C" void kernel_launch(void* const* d_in, const int* in_sizes, int n_in,
                              void* d_out, int out_size, void* d_ws, size_t ws_size,
                              hipStream_t stream) {
    const float* X = (const float*)d_in[0];
    const float* C = (const float*)d_in[1];
    const float* W = (const float*)d_in[2];
    float* out = (float*)d_out;
    int n = in_sizes[0] / D_DIM;        // 500000
    int k_total = in_sizes[1] / D_DIM;  // 512

    int nsegmax = k_total + (n + SEGROWS - 1) / SEGROWS;
    int nblk = (n + 255) / 256;
    int ntiles = (n + RPT - 1) / RPT;
    int agrid = ntiles < AGRID_MAX ? ntiles : AGRID_MAX;

    char* ws = (char*)d_ws;
    int*            count   = (int*)ws;                      // [0,2048)
    float*          inertia = (float*)(ws + 2048);
    int*            segmeta = (int*)(ws + 2056);
    int*            workctr = (int*)(ws + 2060);
    float*          cchalf  = (float*)(ws + 2560);
    int*            offset  = (int*)(ws + 8192);
    unsigned short* Cb      = (unsigned short*)(ws + 12288); // 64 KB

    size_t base = 81920;
    size_t x16_bytes = (size_t)n * 128;                      // 64 MB bf16 rows
    size_t full_tab  = base + x16_bytes;
    size_t ownoff    = full_tab + (size_t)n * 12 +
                       (size_t)AGRID_MAX * K_CLUS * 4 + (size_t)nsegmax * 4;
    size_t needed_full = ownoff + (size_t)ntiles * 4;

    if (ws_size >= needed_full) {
        uint4* X16    = (uint4*)(ws + base);
        int* yv       = (int*)(ws + full_tab);
        int* lrank    = (int*)(ws + full_tab + (size_t)n * 4);
        int* sorted   = (int*)(ws + full_tab + (size_t)n * 8);
        int* baseTab  = (int*)(ws + full_tab + (size_t)n * 12);
        int* segKS    = (int*)(ws + full_tab + (size_t)n * 12 +
                               (size_t)AGRID_MAX * K_CLUS * 4);
        int* tileOwner = (int*)(ws + ownoff);

        cc_kernel<<<6, 256, 0, stream>>>(C, cchalf, Cb, k_total,
                                         (int*)ws, out, out_size);
        assign_mfma<<<agrid, 512, 0, stream>>>(X, Cb, cchalf, yv, lrank, baseTab,
                                               count, inertia, X16, workctr,
                                               tileOwner, n, ntiles);
        prefix_kernel<<<1, K_CLUS, 0, stream>>>(count, offset, segKS, segmeta,
                                                inertia, out);
        scatter_kernel<<<nblk, 256, 0, stream>>>(yv, lrank, offset, baseTab,
                                                 tileOwner, sorted, n);
        cluster_accum_v3<<<nsegmax, 256, 0, stream>>>(X16, W, sorted, offset, count,
                                                      segKS, segmeta, out);
    } else {
        int* yv = (int*)(ws + base);
        hipMemsetAsync(ws, 0, 4096, stream);
        hipMemsetAsync(d_out, 0, (size_t)out_size * sizeof(float), stream);
        cc_kernel<<<6, 256, 0, stream>>>(C, cchalf, Cb, k_total,
                                         (int*)ws, out, out_size);
        assign_scalar<<<nblk, 256, 0, stream>>>(X, C, cchalf, yv, count, inertia, n);
        accum_atomic_kernel<<<nblk, 256, 0, stream>>>(X, W, yv, out, n);
        finalize_kernel<<<1, D_DIM, 0, stream>>>(inertia, out);
    }
}

// Round 14
// 194.110 us; speedup vs baseline: 1.2305x; 1.2305x over previous
//
#include <hip/hip_runtime.h>
#include <hip/hip_bf16.h>

// N=500000, D=64, K=512 (fp32 in/out).
// out rows: [0,K)=xw_sum, [K,2K)=w_sum, row 2K = inertia broadcast to 64 cols.

#define D_DIM 64
#define K_CLUS 512
#define RPT 128           // X rows per tile in assign
#define AGRID_MAX 1024    // assign grid (4 blocks/CU)
#define SEGROWS 64        // rows per accumulation segment (balanced)

typedef __attribute__((ext_vector_type(8))) short short8;
typedef __attribute__((ext_vector_type(4))) float f32x4;

__device__ inline float dot4sq(float4 a) {
    return a.x * a.x + a.y * a.y + a.z * a.z + a.w * a.w;
}
__device__ inline unsigned short bfb(float f) {   // fp32 -> bf16 bits, RNE
    unsigned int u = __float_as_uint(f);
    return (unsigned short)((u + 0x7FFFu + ((u >> 16) & 1u)) >> 16);
}
__device__ inline short8 pack8f(float4 a, float4 b) {
    union { short8 s; __hip_bfloat162 q[4]; } r;
    r.q[0] = __float22bfloat162_rn(make_float2(a.x, a.y));
    r.q[1] = __float22bfloat162_rn(make_float2(a.z, a.w));
    r.q[2] = __float22bfloat162_rn(make_float2(b.x, b.y));
    r.q[3] = __float22bfloat162_rn(make_float2(b.z, b.w));
    return r.s;
}
__device__ inline float bfhi(unsigned u) { return __uint_as_float(u & 0xFFFF0000u); }
__device__ inline float bflo(unsigned u) { return __uint_as_float(u << 16); }

// -------- Kernel 1: cc + bf16 pack of C + (fused) zero ws page & d_out --------
// grid = 6 x 256: blocks 0,1 = cc; block 2 = zero ws[0..4096); blocks 3..5 = zero out.
// NOTE: cchalf lives at ws+4608, OUTSIDE the zeroed page (no intra-kernel race).
__global__ __launch_bounds__(256) void cc_kernel(
        const float* __restrict__ C, float* __restrict__ CChalf,
        unsigned short* __restrict__ Cb, int k_total,
        int* __restrict__ wspage, float* __restrict__ out, int out_sz) {
    int b = blockIdx.x, tid = threadIdx.x;
    if (b < 2) {
        int k = b * 256 + tid;
        if (k >= k_total) return;
        const float4* cp = (const float4*)(C + (size_t)k * D_DIM);
        unsigned short* ob = Cb + (size_t)k * D_DIM;
        float s = 0.f;
#pragma unroll
        for (int i = 0; i < 16; ++i) {
            float4 c = cp[i];
            s += dot4sq(c);
            ob[4 * i + 0] = bfb(c.x); ob[4 * i + 1] = bfb(c.y);
            ob[4 * i + 2] = bfb(c.z); ob[4 * i + 3] = bfb(c.w);
        }
        CChalf[k] = 0.5f * s;
    } else if (b == 2) {
        int4 z = {0, 0, 0, 0};
        ((int4*)wspage)[tid] = z;                 // 256 x 16B = 4096B
    } else {
        float4 z = {0.f, 0.f, 0.f, 0.f};
        float4* o4 = (float4*)out;
        int n4 = out_sz >> 2;
        for (int i = (b - 3) * 256 + tid; i < n4; i += 768) o4[i] = z;
    }
}

// ---------------- Kernel 2: MFMA assignment (R11 structure) ----------------
// Wave w owns clusters [w*64,(w+1)*64) as MFMA A-frags in registers; X tiles
// (128 rows bf16, XOR-swizzled) staged in LDS as B-frags; chained-acc MFMA.
// Static grid-stride tiles; merge distributed across all 8 waves.
__global__ __launch_bounds__(512, 4) void assign_mfma(
        const float* __restrict__ X, const unsigned short* __restrict__ Cb,
        const float* __restrict__ CChalf, int* __restrict__ y,
        int* __restrict__ lrank, int* __restrict__ baseTab,
        int* __restrict__ count, float* __restrict__ inertia_ws,
        uint4* __restrict__ X16, int n, int ntiles) {
    __shared__ __align__(16) char xb_lds[RPT * 128];        // 16 KB bf16, swizzled
    __shared__ __align__(16) unsigned int partial[RPT][8];  // 4 KB keys
    __shared__ float xs_lds[2][RPT];                        // 1 KB ||x||^2, dbuf
    __shared__ int lhist[K_CLUS];                           // 2 KB local histogram

    int tid = threadIdx.x;
    lhist[tid] = 0;

    int lane = tid & 63, wid = tid >> 6;
    int c15 = lane & 15, g = lane >> 4;
    int wbase = wid * 64;

    short8 cf0[4], cf1[4];
    f32x4 nc[4];                           // acc init = -0.5||c||^2 per reg slot
#pragma unroll
    for (int ct = 0; ct < 4; ++ct) {
        const char* cp = (const char*)(Cb + (size_t)(wbase + ct * 16 + c15) * D_DIM);
        cf0[ct] = *(const short8*)(cp + (g << 4));          // k = 8g..8g+7
        cf1[ct] = *(const short8*)(cp + 64 + (g << 4));     // k = 32+8g..
#pragma unroll
        for (int r2 = 0; r2 < 4; ++r2)
            nc[ct][r2] = -CChalf[wbase + ct * 16 + (g << 2) + r2];
    }

    // staging: thread covers 32B of row srow (A) and row 64+srow (B)
    int srow = tid >> 3;
    int sb = (tid & 7) << 4;
    int sf = (tid & 7) << 3;
    unsigned swz = ((unsigned)(srow & 7)) << 4;   // (srow+64)&7 == srow&7

    float4 a0 = {0,0,0,0}, a1 = {0,0,0,0}, b0 = {0,0,0,0}, b1 = {0,0,0,0};
    int tile = blockIdx.x;
    if (tile < ntiles) {
        int rA = min(tile * RPT + srow, n - 1);
        int rB = min(tile * RPT + 64 + srow, n - 1);
        const float4* xa = (const float4*)(X + (size_t)rA * D_DIM + sf);
        const float4* xb = (const float4*)(X + (size_t)rB * D_DIM + sf);
        a0 = xa[0]; a1 = xa[1]; b0 = xb[0]; b1 = xb[1];
    }
    float iner = 0.f;
    int it = 0;

    for (; tile < ntiles; tile += gridDim.x, ++it) {
        int par = it & 1;
        int rA = min(tile * RPT + srow, n - 1);
        int rB = min(tile * RPT + 64 + srow, n - 1);
        short8 pA = pack8f(a0, a1);
        short8 pB = pack8f(b0, b1);
        *(short8*)(xb_lds + (srow << 7) + (sb ^ swz)) = pA;
        *(short8*)(xb_lds + ((64 + srow) << 7) + (sb ^ swz)) = pB;
        float psA = dot4sq(a0) + dot4sq(a1);
        float psB = dot4sq(b0) + dot4sq(b1);
        psA += __shfl_xor(psA, 1); psA += __shfl_xor(psA, 2); psA += __shfl_xor(psA, 4);
        psB += __shfl_xor(psB, 1); psB += __shfl_xor(psB, 2); psB += __shfl_xor(psB, 4);
        if ((tid & 7) == 0) {
            xs_lds[par][srow] = psA;
            xs_lds[par][64 + srow] = psB;
        }
        __syncthreads();                                   // stage visible

        // X16 stores: drain during the sweep
        union { short8 s8; uint4 u4; } cA, cB;
        cA.s8 = pA; cB.s8 = pB;
        X16[(size_t)rA * 8 + (tid & 7)] = cA.u4;
        X16[(size_t)rB * 8 + (tid & 7)] = cB.u4;

        // prefetch next tile's X rows (hides under sweep)
        int ntile = tile + gridDim.x;
        if (ntile < ntiles) {
            int nA = min(ntile * RPT + srow, n - 1);
            int nB = min(ntile * RPT + 64 + srow, n - 1);
            const float4* xa = (const float4*)(X + (size_t)nA * D_DIM + sf);
            const float4* xb = (const float4*)(X + (size_t)nB * D_DIM + sf);
            a0 = xa[0]; a1 = xa[1]; b0 = xb[0]; b1 = xb[1];
        }

        // ---- sweep: 8 row-subtiles x wave's 64 clusters ----
#pragma unroll
        for (int s = 0; s < 8; ++s) {
            int arow = s * 16 + c15;
            const char* ab = xb_lds + (arow << 7);
            unsigned asw = ((unsigned)(arow & 7)) << 4;
            short8 xa = *(const short8*)(ab + ((g << 4) ^ asw));
            short8 xbv = *(const short8*)(ab + ((64 + (g << 4)) ^ asw));

            float best = -3.4e38f;
            int bpos = 0;
#pragma unroll
            for (int ct = 0; ct < 4; ++ct) {
                f32x4 acc = __builtin_amdgcn_mfma_f32_16x16x32_bf16(cf0[ct], xa, nc[ct], 0, 0, 0);
                acc = __builtin_amdgcn_mfma_f32_16x16x32_bf16(cf1[ct], xbv, acc, 0, 0, 0);
                float sc0 = acc[0], sc1 = acc[1], sc2 = acc[2], sc3 = acc[3];
                bool b01 = sc1 > sc0;  float v01 = b01 ? sc1 : sc0;  int p01 = b01 ? 1 : 0;
                bool b23 = sc3 > sc2;  float v23 = b23 ? sc3 : sc2;  int p23 = b23 ? 3 : 2;
                bool bq  = v23 > v01;  float vq  = bq ? v23 : v01;   int pq  = bq ? p23 : p01;
                if (vq > best) { best = vq; bpos = (ct << 2) + pq; }
            }
            int kg = wbase + ((bpos >> 2) << 4) + (g << 2) + (bpos & 3);
            unsigned u = __float_as_uint(best);
            unsigned mono = u ^ ((u & 0x80000000u) ? 0xFFFFFFFFu : 0x80000000u);
            unsigned key = (mono & 0xFFFFFE00u) | ((unsigned)kg ^ 0x1FFu);
            unsigned o = (unsigned)__shfl_xor((int)key, 16); key = key > o ? key : o;
            o = (unsigned)__shfl_xor((int)key, 32); key = key > o ? key : o;
            if (g == 0) partial[s * 16 + c15][wid] = key;
        }
        __syncthreads();                                   // partials visible

        // ---- merge: distributed, wave w handles rows [16w,16w+16) ----
        if (g == 0) {
            int r = (wid << 4) + c15;
            int grow = tile * RPT + r;
            if (grow < n) {
                const uint4* pp = (const uint4*)&partial[r][0];
                uint4 p0 = pp[0], p1 = pp[1];
                unsigned key = p0.x;
                key = key > p0.y ? key : p0.y;
                key = key > p0.z ? key : p0.z;
                key = key > p0.w ? key : p0.w;
                key = key > p1.x ? key : p1.x;
                key = key > p1.y ? key : p1.y;
                key = key > p1.z ? key : p1.z;
                key = key > p1.w ? key : p1.w;
                int kg = (int)((key & 0x1FFu) ^ 0x1FFu);
                unsigned m2 = (key & 0xFFFFFE00u) | 0x100u;
                unsigned ub = (m2 & 0x80000000u) ? (m2 ^ 0x80000000u) : ~m2;
                float sbest = __uint_as_float(ub);
                float xx = xs_lds[par][r];
                y[grow] = kg;
                lrank[grow] = atomicAdd(&lhist[kg], 1);
                iner += sqrtf(fmaxf(xx - 2.f * sbest, 0.f) * (1.0f / 64.0f));
            }
        }
    }

    __syncthreads();                       // once: full sync before flush
    int b = atomicAdd(count + tid, lhist[tid]);
    baseTab[blockIdx.x * K_CLUS + tid] = b;

#pragma unroll
    for (int off = 1; off < 64; off <<= 1) iner += __shfl_xor(iner, off);
    if (lane == 0) atomicAdd(inertia_ws, iner);
}

// ------- Kernel 3: prefix sums + segment worklist + (fused) inertia row -------
__global__ __launch_bounds__(K_CLUS) void prefix_kernel(
        const int* __restrict__ count, int* __restrict__ offset,
        int* __restrict__ segKS, int* __restrict__ segmeta,
        const float* __restrict__ inertia_ws, float* __restrict__ out) {
    __shared__ int tmp[K_CLUS];
    __shared__ int tns[K_CLUS];
    int t = threadIdx.x;
    int c = count[t];
    int ns = (c + SEGROWS - 1) / SEGROWS;
    tmp[t] = c; tns[t] = ns;
    __syncthreads();
    for (int s = 1; s < K_CLUS; s <<= 1) {
        int v1 = (t >= s) ? tmp[t - s] : 0;
        int v2 = (t >= s) ? tns[t - s] : 0;
        __syncthreads();
        tmp[t] += v1; tns[t] += v2;
        __syncthreads();
    }
    offset[t] = tmp[t] - c;                 // exclusive row offset
    int so = tns[t] - ns;                   // exclusive segment offset
    for (int s = 0; s < ns; ++s) segKS[so + s] = (t << 16) | s;
    if (t == K_CLUS - 1) segmeta[0] = tns[t];
    if (t < D_DIM) out[(size_t)(2 * K_CLUS) * D_DIM + t] = *inertia_ws;  // finalize
}

// ---------------- Kernel 4: scatter rows into cluster-sorted order ----------------
__global__ __launch_bounds__(256) void scatter_kernel(
        const int* __restrict__ y, const int* __restrict__ lrank,
        const int* __restrict__ offset, const int* __restrict__ baseTab,
        int* __restrict__ sorted, int n, int agrid) {
    int row = blockIdx.x * blockDim.x + threadIdx.x;
    if (row >= n) return;
    int k = y[row];
    int blk = (row >> 7) % agrid;     // RPT=128 rows per tile, static mapping
    sorted[offset[k] + baseTab[blk * K_CLUS + k] + lrank[row]] = row;
}

// ------- Kernel 5: compressed gather accumulation -------
__global__ __launch_bounds__(256, 6) void cluster_accum_v3(
        const uint4* __restrict__ X16, const float* __restrict__ W,
        const int* __restrict__ sorted, const int* __restrict__ offset,
        const int* __restrict__ count, const int* __restrict__ segKS,
        const int* __restrict__ segmeta, float* __restrict__ out) {
    int bid = blockIdx.x;
    if (bid >= segmeta[0]) return;
    int v = segKS[bid];
    int k = v >> 16, s = v & 0xFFFF;
    int cnt = count[k];
    int lo = s * SEGROWS;
    int m = min(cnt - lo, SEGROWS);
    int start = offset[k] + lo;
    int lane = threadIdx.x & 63, w = threadIdx.x >> 6;
    int grp = (w << 2) | (lane >> 4);       // 0..15
    int l8 = lane & 7;
    int h = (lane >> 3) & 1;
    int g4 = grp * 4;
    const float4* W4 = (const float4*)W;

    int i0 = g4 + h;
    int i1 = g4 + 2 + h;
    int r0 = (i0 < m) ? sorted[start + i0] : -1;
    int r1 = (i1 < m) ? sorted[start + i1] : -1;

    uint4 zz = {0u, 0u, 0u, 0u};
    float4 fz = {0.f, 0.f, 0.f, 0.f};
    uint4 xq0 = zz, xq1 = zz;
    float4 wa0 = fz, wb0 = fz, wa1 = fz, wb1 = fz;
    if (r0 >= 0) {
        xq0 = X16[(size_t)r0 * 8 + l8];
        wa0 = W4[(size_t)r0 * 16 + 2 * l8];
        wb0 = W4[(size_t)r0 * 16 + 2 * l8 + 1];
    }
    if (r1 >= 0) {
        xq1 = X16[(size_t)r1 * 8 + l8];
        wa1 = W4[(size_t)r1 * 16 + 2 * l8];
        wb1 = W4[(size_t)r1 * 16 + 2 * l8 + 1];
    }

    float axw[8], aww[8];
#pragma unroll
    for (int j = 0; j < 8; ++j) { axw[j] = 0.f; aww[j] = 0.f; }

#pragma unroll
    for (int r = 0; r < 2; ++r) {
        uint4 xq = r ? xq1 : xq0;
        float4 wa = r ? wa1 : wa0;
        float4 wb = r ? wb1 : wb0;
        float xf[8];
        xf[0] = bflo(xq.x); xf[1] = bfhi(xq.x);
        xf[2] = bflo(xq.y); xf[3] = bfhi(xq.y);
        xf[4] = bflo(xq.z); xf[5] = bfhi(xq.z);
        xf[6] = bflo(xq.w); xf[7] = bfhi(xq.w);
        axw[0] = fmaf(xf[0], wa.x, axw[0]); aww[0] += wa.x;
        axw[1] = fmaf(xf[1], wa.y, axw[1]); aww[1] += wa.y;
        axw[2] = fmaf(xf[2], wa.z, axw[2]); aww[2] += wa.z;
        axw[3] = fmaf(xf[3], wa.w, axw[3]); aww[3] += wa.w;
        axw[4] = fmaf(xf[4], wb.x, axw[4]); aww[4] += wb.x;
        axw[5] = fmaf(xf[5], wb.y, axw[5]); aww[5] += wb.y;
        axw[6] = fmaf(xf[6], wb.z, axw[6]); aww[6] += wb.z;
        axw[7] = fmaf(xf[7], wb.w, axw[7]); aww[7] += wb.w;
    }
#pragma unroll
    for (int j = 0; j < 8; ++j) {
        axw[j] += __shfl_xor(axw[j], 8);
        aww[j] += __shfl_xor(aww[j], 8);
    }

    __shared__ float sxw[16][D_DIM];
    __shared__ float sww[16][D_DIM];
    if (h == 0) {
#pragma unroll
        for (int j = 0; j < 8; ++j) {
            sxw[grp][8 * l8 + j] = axw[j];
            sww[grp][8 * l8 + j] = aww[j];
        }
    }
    __syncthreads();
    int t = threadIdx.x;
    if (t < 128) {
        int half = t >> 6, d = t & 63;
        const float(*src)[D_DIM] = half ? sww : sxw;
        float acc = 0.f;
#pragma unroll
        for (int jg = 0; jg < 16; ++jg) acc += src[jg][d];
        atomicAdd(out + (size_t)(half ? K_CLUS + k : k) * D_DIM + d, acc);
    }
}

// ---------------- Fallback-only kernels ----------------
__global__ void finalize_kernel(const float* __restrict__ inertia_ws, float* __restrict__ out) {
    out[(size_t)(2 * K_CLUS) * D_DIM + threadIdx.x] = *inertia_ws;
}

__global__ __launch_bounds__(256) void assign_scalar(
        const float* __restrict__ X, const float* __restrict__ C,
        const float* __restrict__ CChalf, int* __restrict__ y,
        int* __restrict__ count, float* __restrict__ inertia_ws, int n) {
    int row = blockIdx.x * blockDim.x + threadIdx.x;
    float mind = 0.f;
    if (row < n) {
        float4 x[16];
        const float4* xp = (const float4*)(X + (size_t)row * D_DIM);
#pragma unroll
        for (int i = 0; i < 16; ++i) x[i] = xp[i];
        float xx = 0.f;
#pragma unroll
        for (int i = 0; i < 16; ++i) xx += dot4sq(x[i]);
        float best = -3.4e38f;
        int bestk = 0;
        for (int k = 0; k < K_CLUS; ++k) {
            const float4* cp = (const float4*)(C + (size_t)k * D_DIM);
            float s0 = 0.f;
#pragma unroll
            for (int i = 0; i < 16; ++i) {
                float4 c = cp[i];
                s0 += x[i].x * c.x + x[i].y * c.y + x[i].z * c.z + x[i].w * c.w;
            }
            float sc = s0 - CChalf[k];
            if (sc > best) { best = sc; bestk = k; }
        }
        y[row] = bestk;
        atomicAdd(&count[bestk], 1);
        mind = sqrtf(fmaxf(xx - 2.f * best, 0.f) * (1.0f / 64.0f));
    }
    float s = mind;
#pragma unroll
    for (int off = 32; off > 0; off >>= 1) s += __shfl_xor(s, off);
    __shared__ float wsum[4];
    int w = threadIdx.x >> 6;
    if ((threadIdx.x & 63) == 0) wsum[w] = s;
    __syncthreads();
    if (threadIdx.x == 0)
        atomicAdd(inertia_ws, wsum[0] + wsum[1] + wsum[2] + wsum[3]);
}

__global__ __launch_bounds__(256) void accum_atomic_kernel(
        const float* __restrict__ X, const float* __restrict__ W,
        const int* __restrict__ y, float* __restrict__ out, int n) {
    int row = blockIdx.x * blockDim.x + threadIdx.x;
    if (row >= n) return;
    int k = y[row];
    const float4* xp = (const float4*)(X + (size_t)row * D_DIM);
    const float4* wp = (const float4*)(W + (size_t)row * D_DIM);
    float* xw = out + (size_t)k * D_DIM;
    float* wsv = out + (size_t)(K_CLUS + k) * D_DIM;
#pragma unroll
    for (int i = 0; i < 16; ++i) {
        float4 x = xp[i];
        float4 wq = wp[i];
        atomicAdd(xw + 4 * i + 0, x.x * wq.x);
        atomicAdd(xw + 4 * i + 1, x.y * wq.y);
        atomicAdd(xw + 4 * i + 2, x.z * wq.z);
        atomicAdd(xw + 4 * i + 3, x.w * wq.w);
        atomicAdd(wsv + 4 * i + 0, wq.x);
        atomicAdd(wsv + 4 * i + 1, wq.y);
        atomicAdd(wsv + 4 * i + 2, wq.z);
        atomicAdd(wsv + 4 * i + 3, wq.w);
    }
}

extern "C" void kernel_launch(void* const* d_in, const int* in_sizes, int n_in,
                              void* d_out, int out_size, void* d_ws, size_t ws_size,
                              hipStream_t stream) {
    const float* X = (const float*)d_in[0];
    const float* C = (const float*)d_in[1];
    const float* W = (const float*)d_in[2];
    float* out = (float*)d_out;
    int n = in_sizes[0] / D_DIM;        // 500000
    int k_total = in_sizes[1] / D_DIM;  // 512

    int nsegmax = k_total + (n + SEGROWS - 1) / SEGROWS;
    int nblk = (n + 255) / 256;
    int ntiles = (n + RPT - 1) / RPT;
    int agrid = ntiles < AGRID_MAX ? ntiles : AGRID_MAX;

    char* ws = (char*)d_ws;
    int*            count   = (int*)ws;                      // [0,2048)
    float*          inertia = (float*)(ws + 2048);
    int*            segmeta = (int*)(ws + 2056);
    float*          cchalf  = (float*)(ws + 4608);           // OUTSIDE zeroed page
    int*            offset  = (int*)(ws + 8192);
    unsigned short* Cb      = (unsigned short*)(ws + 12288); // 64 KB

    size_t base = 81920;
    size_t x16_bytes = (size_t)n * 128;                      // 64 MB bf16 rows
    size_t full_tab  = base + x16_bytes;
    size_t needed_full = full_tab + (size_t)n * 12 +
                         (size_t)AGRID_MAX * K_CLUS * 4 + (size_t)nsegmax * 4;

    if (ws_size >= needed_full) {
        uint4* X16    = (uint4*)(ws + base);
        int* yv       = (int*)(ws + full_tab);
        int* lrank    = (int*)(ws + full_tab + (size_t)n * 4);
        int* sorted   = (int*)(ws + full_tab + (size_t)n * 8);
        int* baseTab  = (int*)(ws + full_tab + (size_t)n * 12);
        int* segKS    = (int*)(ws + full_tab + (size_t)n * 12 +
                               (size_t)AGRID_MAX * K_CLUS * 4);

        cc_kernel<<<6, 256, 0, stream>>>(C, cchalf, Cb, k_total,
                                         (int*)ws, out, out_size);
        assign_mfma<<<agrid, 512, 0, stream>>>(X, Cb, cchalf, yv, lrank, baseTab,
                                               count, inertia, X16, n, ntiles);
        prefix_kernel<<<1, K_CLUS, 0, stream>>>(count, offset, segKS, segmeta,
                                                inertia, out);
        scatter_kernel<<<nblk, 256, 0, stream>>>(yv, lrank, offset, baseTab,
                                                 sorted, n, agrid);
        cluster_accum_v3<<<nsegmax, 256, 0, stream>>>(X16, W, sorted, offset, count,
                                                      segKS, segmeta, out);
    } else {
        int* yv = (int*)(ws + base);
        hipMemsetAsync(ws, 0, 4096, stream);
        hipMemsetAsync(d_out, 0, (size_t)out_size * sizeof(float), stream);
        cc_kernel<<<6, 256, 0, stream>>>(C, cchalf, Cb, k_total,
                                         (int*)ws, out, out_size);
        assign_scalar<<<nblk, 256, 0, stream>>>(X, C, cchalf, yv, count, inertia, n);
        accum_atomic_kernel<<<nblk, 256, 0, stream>>>(X, W, yv, out, n);
        finalize_kernel<<<1, D_DIM, 0, stream>>>(inertia, out);
    }
}

// Round 15
// 128.948 us; speedup vs baseline: 1.8523x; 1.5053x over previous
//
#include <hip/hip_runtime.h>
#include <hip/hip_bf16.h>

// N=500000, D=64, K=512 (fp32 in/out).
// out rows: [0,K)=xw_sum, [K,2K)=w_sum, row 2K = inertia broadcast to 64 cols.
// CHAMPION REVERT: exact source of the 130.3us run (Round-11 bench).

#define D_DIM 64
#define K_CLUS 512
#define RPT 128           // X rows per tile in assign
#define AGRID_MAX 1024    // assign grid (4 blocks/CU)
#define SEGROWS 64        // rows per accumulation segment (balanced)

typedef __attribute__((ext_vector_type(8))) short short8;
typedef __attribute__((ext_vector_type(4))) float f32x4;

__device__ inline float dot4sq(float4 a) {
    return a.x * a.x + a.y * a.y + a.z * a.z + a.w * a.w;
}
__device__ inline unsigned short bfb(float f) {   // fp32 -> bf16 bits, RNE
    unsigned int u = __float_as_uint(f);
    return (unsigned short)((u + 0x7FFFu + ((u >> 16) & 1u)) >> 16);
}
__device__ inline short8 pack8f(float4 a, float4 b) {
    union { short8 s; __hip_bfloat162 q[4]; } r;
    r.q[0] = __float22bfloat162_rn(make_float2(a.x, a.y));
    r.q[1] = __float22bfloat162_rn(make_float2(a.z, a.w));
    r.q[2] = __float22bfloat162_rn(make_float2(b.x, b.y));
    r.q[3] = __float22bfloat162_rn(make_float2(b.z, b.w));
    return r.s;
}
__device__ inline float bfhi(unsigned u) { return __uint_as_float(u & 0xFFFF0000u); }
__device__ inline float bflo(unsigned u) { return __uint_as_float(u << 16); }

// ---------------- Kernel 1: half-norms + bf16 pack of centroids ----------------
__global__ void cc_kernel(const float* __restrict__ C, float* __restrict__ CChalf,
                          unsigned short* __restrict__ Cb, int k_total) {
    int k = blockIdx.x * blockDim.x + threadIdx.x;
    if (k >= k_total) return;
    const float4* cp = (const float4*)(C + (size_t)k * D_DIM);
    unsigned short* ob = Cb + (size_t)k * D_DIM;
    float s = 0.f;
#pragma unroll
    for (int i = 0; i < 16; ++i) {
        float4 c = cp[i];
        s += dot4sq(c);
        ob[4 * i + 0] = bfb(c.x); ob[4 * i + 1] = bfb(c.y);
        ob[4 * i + 2] = bfb(c.z); ob[4 * i + 3] = bfb(c.w);
    }
    CChalf[k] = 0.5f * s;
}

// ---------------- Kernel 2: MFMA assignment, C-in-registers ----------------
// Wave w owns clusters [w*64,(w+1)*64) as MFMA A-frags in registers; X tiles
// (128 rows bf16, XOR-swizzled) staged in LDS as B-frags; chained-acc MFMA.
// X16 stores issued after the stage barrier; merge on waves 0-1 (tid<RPT).
__global__ __launch_bounds__(512, 4) void assign_mfma(
        const float* __restrict__ X, const unsigned short* __restrict__ Cb,
        const float* __restrict__ CChalf, int* __restrict__ y,
        int* __restrict__ lrank, int* __restrict__ baseTab,
        int* __restrict__ count, float* __restrict__ inertia_ws,
        uint4* __restrict__ X16, int n, int ntiles) {
    __shared__ __align__(16) char xb_lds[RPT * 128];        // 16 KB bf16, swizzled
    __shared__ __align__(16) unsigned int partial[RPT][8];  // 4 KB keys
    __shared__ float xs_lds[2][RPT];                        // 1 KB ||x||^2, dbuf
    __shared__ int lhist[K_CLUS];                           // 2 KB local histogram

    int tid = threadIdx.x;
    lhist[tid] = 0;

    int lane = tid & 63, wid = tid >> 6;
    int c15 = lane & 15, g = lane >> 4;
    int wbase = wid * 64;

    short8 cf0[4], cf1[4];
    f32x4 nc[4];                           // acc init = -0.5||c||^2 per reg slot
#pragma unroll
    for (int ct = 0; ct < 4; ++ct) {
        const char* cp = (const char*)(Cb + (size_t)(wbase + ct * 16 + c15) * D_DIM);
        cf0[ct] = *(const short8*)(cp + (g << 4));          // k = 8g..8g+7
        cf1[ct] = *(const short8*)(cp + 64 + (g << 4));     // k = 32+8g..
#pragma unroll
        for (int r2 = 0; r2 < 4; ++r2)
            nc[ct][r2] = -CChalf[wbase + ct * 16 + (g << 2) + r2];
    }

    // staging: thread covers 32B of row srow (A) and row 64+srow (B)
    int srow = tid >> 3;
    int sb = (tid & 7) << 4;
    int sf = (tid & 7) << 3;
    unsigned swz = ((unsigned)(srow & 7)) << 4;   // (srow+64)&7 == srow&7

    float4 a0 = {0,0,0,0}, a1 = {0,0,0,0}, b0 = {0,0,0,0}, b1 = {0,0,0,0};
    int tile = blockIdx.x;
    if (tile < ntiles) {
        int rA = min(tile * RPT + srow, n - 1);
        int rB = min(tile * RPT + 64 + srow, n - 1);
        const float4* xa = (const float4*)(X + (size_t)rA * D_DIM + sf);
        const float4* xb = (const float4*)(X + (size_t)rB * D_DIM + sf);
        a0 = xa[0]; a1 = xa[1]; b0 = xb[0]; b1 = xb[1];
    }
    float iner = 0.f;
    int it = 0;

    for (; tile < ntiles; tile += gridDim.x, ++it) {
        int par = it & 1;
        int rA = min(tile * RPT + srow, n - 1);
        int rB = min(tile * RPT + 64 + srow, n - 1);
        short8 pA = pack8f(a0, a1);
        short8 pB = pack8f(b0, b1);
        *(short8*)(xb_lds + (srow << 7) + (sb ^ swz)) = pA;
        *(short8*)(xb_lds + ((64 + srow) << 7) + (sb ^ swz)) = pB;
        float psA = dot4sq(a0) + dot4sq(a1);
        float psB = dot4sq(b0) + dot4sq(b1);
        psA += __shfl_xor(psA, 1); psA += __shfl_xor(psA, 2); psA += __shfl_xor(psA, 4);
        psB += __shfl_xor(psB, 1); psB += __shfl_xor(psB, 2); psB += __shfl_xor(psB, 4);
        if ((tid & 7) == 0) {
            xs_lds[par][srow] = psA;
            xs_lds[par][64 + srow] = psB;
        }
        __syncthreads();                                   // stage visible

        // X16 stores AFTER the barrier: drain during the sweep
        union { short8 s8; uint4 u4; } cA, cB;
        cA.s8 = pA; cB.s8 = pB;
        X16[(size_t)rA * 8 + (tid & 7)] = cA.u4;
        X16[(size_t)rB * 8 + (tid & 7)] = cB.u4;

        // issue next tile's loads (latency hides under sweep)
        int ntile = tile + gridDim.x;
        if (ntile < ntiles) {
            int nA = min(ntile * RPT + srow, n - 1);
            int nB = min(ntile * RPT + 64 + srow, n - 1);
            const float4* xa = (const float4*)(X + (size_t)nA * D_DIM + sf);
            const float4* xb = (const float4*)(X + (size_t)nB * D_DIM + sf);
            a0 = xa[0]; a1 = xa[1]; b0 = xb[0]; b1 = xb[1];
        }

        // ---- sweep: 8 row-subtiles x wave's 64 clusters ----
#pragma unroll
        for (int s = 0; s < 8; ++s) {
            int arow = s * 16 + c15;                       // x-row (B col)
            const char* ab = xb_lds + (arow << 7);
            unsigned asw = ((unsigned)(arow & 7)) << 4;
            short8 xa = *(const short8*)(ab + ((g << 4) ^ asw));
            short8 xbv = *(const short8*)(ab + ((64 + (g << 4)) ^ asw));

            float best = -3.4e38f;
            int bpos = 0;
#pragma unroll
            for (int ct = 0; ct < 4; ++ct) {
                // chained acc: K-halves summed inside the MFMA pipe
                f32x4 acc = __builtin_amdgcn_mfma_f32_16x16x32_bf16(cf0[ct], xa, nc[ct], 0, 0, 0);
                acc = __builtin_amdgcn_mfma_f32_16x16x32_bf16(cf1[ct], xbv, acc, 0, 0, 0);
                float sc0 = acc[0], sc1 = acc[1], sc2 = acc[2], sc3 = acc[3];
                bool b01 = sc1 > sc0;  float v01 = b01 ? sc1 : sc0;  int p01 = b01 ? 1 : 0;
                bool b23 = sc3 > sc2;  float v23 = b23 ? sc3 : sc2;  int p23 = b23 ? 3 : 2;
                bool bq  = v23 > v01;  float vq  = bq ? v23 : v01;   int pq  = bq ? p23 : p01;
                if (vq > best) { best = vq; bpos = (ct << 2) + pq; }
            }
            int kg = wbase + ((bpos >> 2) << 4) + (g << 2) + (bpos & 3);
            unsigned u = __float_as_uint(best);
            unsigned mono = u ^ ((u & 0x80000000u) ? 0xFFFFFFFFu : 0x80000000u);
            unsigned key = (mono & 0xFFFFFE00u) | ((unsigned)kg ^ 0x1FFu);
            unsigned o = (unsigned)__shfl_xor((int)key, 16); key = key > o ? key : o;
            o = (unsigned)__shfl_xor((int)key, 32); key = key > o ? key : o;
            if (g == 0) partial[s * 16 + c15][wid] = key;
        }
        __syncthreads();                                   // partials visible

        // ---- merge: 128 threads, one row each; rank via LDS atomic ----
        if (tid < RPT) {
            int grow = tile * RPT + tid;
            if (grow < n) {
                const uint4* pp = (const uint4*)&partial[tid][0];
                uint4 p0 = pp[0], p1 = pp[1];
                unsigned key = p0.x;
                key = key > p0.y ? key : p0.y;
                key = key > p0.z ? key : p0.z;
                key = key > p0.w ? key : p0.w;
                key = key > p1.x ? key : p1.x;
                key = key > p1.y ? key : p1.y;
                key = key > p1.z ? key : p1.z;
                key = key > p1.w ? key : p1.w;
                int kg = (int)((key & 0x1FFu) ^ 0x1FFu);
                unsigned m2 = (key & 0xFFFFFE00u) | 0x100u;
                unsigned ub = (m2 & 0x80000000u) ? (m2 ^ 0x80000000u) : ~m2;
                float sbest = __uint_as_float(ub);
                float xx = xs_lds[par][tid];
                y[grow] = kg;
                lrank[grow] = atomicAdd(&lhist[kg], 1);
                iner += sqrtf(fmaxf(xx - 2.f * sbest, 0.f) * (1.0f / 64.0f));
            }
        }
    }

    __syncthreads();
    int b = atomicAdd(count + tid, lhist[tid]);
    baseTab[blockIdx.x * K_CLUS + tid] = b;

    if (wid < 2) {                        // waves 0,1 hold inertia partials
#pragma unroll
        for (int off = 1; off < 64; off <<= 1) iner += __shfl_xor(iner, off);
        if (lane == 0) atomicAdd(inertia_ws, iner);
    }
}

// ------- Kernel 3: prefix sums (offsets) + balanced segment worklist -------
__global__ __launch_bounds__(K_CLUS) void prefix_kernel(
        const int* __restrict__ count, int* __restrict__ offset,
        int* __restrict__ segKS, int* __restrict__ segmeta) {
    __shared__ int tmp[K_CLUS];
    __shared__ int tns[K_CLUS];
    int t = threadIdx.x;
    int c = count[t];
    int ns = (c + SEGROWS - 1) / SEGROWS;
    tmp[t] = c; tns[t] = ns;
    __syncthreads();
    for (int s = 1; s < K_CLUS; s <<= 1) {
        int v1 = (t >= s) ? tmp[t - s] : 0;
        int v2 = (t >= s) ? tns[t - s] : 0;
        __syncthreads();
        tmp[t] += v1; tns[t] += v2;
        __syncthreads();
    }
    offset[t] = tmp[t] - c;                 // exclusive row offset
    int so = tns[t] - ns;                   // exclusive segment offset
    for (int s = 0; s < ns; ++s) segKS[so + s] = (t << 16) | s;
    if (t == K_CLUS - 1) segmeta[0] = tns[t];
}

// ---------------- Kernel 4: scatter rows into cluster-sorted order ----------------
__global__ __launch_bounds__(256) void scatter_kernel(
        const int* __restrict__ y, const int* __restrict__ lrank,
        const int* __restrict__ offset, const int* __restrict__ baseTab,
        int* __restrict__ sorted, int n, int agrid) {
    int row = blockIdx.x * blockDim.x + threadIdx.x;
    if (row >= n) return;
    int k = y[row];
    int blk = (row / RPT) % agrid;    // tile -> assign block id (RPT rows/tile)
    sorted[offset[k] + baseTab[blk * K_CLUS + k] + lrank[row]] = row;
}

// ------- Kernel 5: compressed gather accumulation -------
__global__ __launch_bounds__(256, 6) void cluster_accum_v3(
        const uint4* __restrict__ X16, const float* __restrict__ W,
        const int* __restrict__ sorted, const int* __restrict__ offset,
        const int* __restrict__ count, const int* __restrict__ segKS,
        const int* __restrict__ segmeta, float* __restrict__ out) {
    int bid = blockIdx.x;
    if (bid >= segmeta[0]) return;
    int v = segKS[bid];
    int k = v >> 16, s = v & 0xFFFF;
    int cnt = count[k];
    int lo = s * SEGROWS;
    int m = min(cnt - lo, SEGROWS);
    int start = offset[k] + lo;
    int lane = threadIdx.x & 63, w = threadIdx.x >> 6;
    int grp = (w << 2) | (lane >> 4);       // 0..15
    int l8 = lane & 7;                      // dim block: dims 8*l8..8*l8+7
    int h = (lane >> 3) & 1;                // row half
    int g4 = grp * 4;
    const float4* W4 = (const float4*)W;

    int i0 = g4 + h;
    int i1 = g4 + 2 + h;
    int r0 = (i0 < m) ? sorted[start + i0] : -1;
    int r1 = (i1 < m) ? sorted[start + i1] : -1;

    uint4 zz = {0u, 0u, 0u, 0u};
    float4 fz = {0.f, 0.f, 0.f, 0.f};
    uint4 xq0 = zz, xq1 = zz;
    float4 wa0 = fz, wb0 = fz, wa1 = fz, wb1 = fz;
    if (r0 >= 0) {
        xq0 = X16[(size_t)r0 * 8 + l8];
        wa0 = W4[(size_t)r0 * 16 + 2 * l8];
        wb0 = W4[(size_t)r0 * 16 + 2 * l8 + 1];
    }
    if (r1 >= 0) {
        xq1 = X16[(size_t)r1 * 8 + l8];
        wa1 = W4[(size_t)r1 * 16 + 2 * l8];
        wb1 = W4[(size_t)r1 * 16 + 2 * l8 + 1];
    }

    float axw[8], aww[8];
#pragma unroll
    for (int j = 0; j < 8; ++j) { axw[j] = 0.f; aww[j] = 0.f; }

#pragma unroll
    for (int r = 0; r < 2; ++r) {
        uint4 xq = r ? xq1 : xq0;
        float4 wa = r ? wa1 : wa0;
        float4 wb = r ? wb1 : wb0;
        float xf[8];
        xf[0] = bflo(xq.x); xf[1] = bfhi(xq.x);
        xf[2] = bflo(xq.y); xf[3] = bfhi(xq.y);
        xf[4] = bflo(xq.z); xf[5] = bfhi(xq.z);
        xf[6] = bflo(xq.w); xf[7] = bfhi(xq.w);
        axw[0] = fmaf(xf[0], wa.x, axw[0]); aww[0] += wa.x;
        axw[1] = fmaf(xf[1], wa.y, axw[1]); aww[1] += wa.y;
        axw[2] = fmaf(xf[2], wa.z, axw[2]); aww[2] += wa.z;
        axw[3] = fmaf(xf[3], wa.w, axw[3]); aww[3] += wa.w;
        axw[4] = fmaf(xf[4], wb.x, axw[4]); aww[4] += wb.x;
        axw[5] = fmaf(xf[5], wb.y, axw[5]); aww[5] += wb.y;
        axw[6] = fmaf(xf[6], wb.z, axw[6]); aww[6] += wb.z;
        axw[7] = fmaf(xf[7], wb.w, axw[7]); aww[7] += wb.w;
    }
#pragma unroll
    for (int j = 0; j < 8; ++j) {
        axw[j] += __shfl_xor(axw[j], 8);
        aww[j] += __shfl_xor(aww[j], 8);
    }

    __shared__ float sxw[16][D_DIM];
    __shared__ float sww[16][D_DIM];
    if (h == 0) {
#pragma unroll
        for (int j = 0; j < 8; ++j) {
            sxw[grp][8 * l8 + j] = axw[j];
            sww[grp][8 * l8 + j] = aww[j];
        }
    }
    __syncthreads();
    int t = threadIdx.x;
    if (t < 128) {
        int half = t >> 6, d = t & 63;
        const float(*src)[D_DIM] = half ? sww : sxw;
        float acc = 0.f;
#pragma unroll
        for (int jg = 0; jg < 16; ++jg) acc += src[jg][d];
        atomicAdd(out + (size_t)(half ? K_CLUS + k : k) * D_DIM + d, acc);
    }
}

// ---------------- Kernel 6: broadcast inertia ----------------
__global__ void finalize_kernel(const float* __restrict__ inertia_ws, float* __restrict__ out) {
    out[(size_t)(2 * K_CLUS) * D_DIM + threadIdx.x] = *inertia_ws;
}

// ---------------- Last-resort fallback (tiny ws) ----------------
__global__ __launch_bounds__(256) void assign_scalar(
        const float* __restrict__ X, const float* __restrict__ C,
        const float* __restrict__ CChalf, int* __restrict__ y,
        int* __restrict__ count, float* __restrict__ inertia_ws, int n) {
    int row = blockIdx.x * blockDim.x + threadIdx.x;
    float mind = 0.f;
    if (row < n) {
        float4 x[16];
        const float4* xp = (const float4*)(X + (size_t)row * D_DIM);
#pragma unroll
        for (int i = 0; i < 16; ++i) x[i] = xp[i];
        float xx = 0.f;
#pragma unroll
        for (int i = 0; i < 16; ++i) xx += dot4sq(x[i]);
        float best = -3.4e38f;
        int bestk = 0;
        for (int k = 0; k < K_CLUS; ++k) {
            const float4* cp = (const float4*)(C + (size_t)k * D_DIM);
            float s0 = 0.f;
#pragma unroll
            for (int i = 0; i < 16; ++i) {
                float4 c = cp[i];
                s0 += x[i].x * c.x + x[i].y * c.y + x[i].z * c.z + x[i].w * c.w;
            }
            float sc = s0 - CChalf[k];
            if (sc > best) { best = sc; bestk = k; }
        }
        y[row] = bestk;
        atomicAdd(&count[bestk], 1);
        mind = sqrtf(fmaxf(xx - 2.f * best, 0.f) * (1.0f / 64.0f));
    }
    float s = mind;
#pragma unroll
    for (int off = 32; off > 0; off >>= 1) s += __shfl_xor(s, off);
    __shared__ float wsum[4];
    int w = threadIdx.x >> 6;
    if ((threadIdx.x & 63) == 0) wsum[w] = s;
    __syncthreads();
    if (threadIdx.x == 0)
        atomicAdd(inertia_ws, wsum[0] + wsum[1] + wsum[2] + wsum[3]);
}

__global__ __launch_bounds__(256) void accum_atomic_kernel(
        const float* __restrict__ X, const float* __restrict__ W,
        const int* __restrict__ y, float* __restrict__ out, int n) {
    int row = blockIdx.x * blockDim.x + threadIdx.x;
    if (row >= n) return;
    int k = y[row];
    const float4* xp = (const float4*)(X + (size_t)row * D_DIM);
    const float4* wp = (const float4*)(W + (size_t)row * D_DIM);
    float* xw = out + (size_t)k * D_DIM;
    float* wsv = out + (size_t)(K_CLUS + k) * D_DIM;
#pragma unroll
    for (int i = 0; i < 16; ++i) {
        float4 x = xp[i];
        float4 wq = wp[i];
        atomicAdd(xw + 4 * i + 0, x.x * wq.x);
        atomicAdd(xw + 4 * i + 1, x.y * wq.y);
        atomicAdd(xw + 4 * i + 2, x.z * wq.z);
        atomicAdd(xw + 4 * i + 3, x.w * wq.w);
        atomicAdd(wsv + 4 * i + 0, wq.x);
        atomicAdd(wsv + 4 * i + 1, wq.y);
        atomicAdd(wsv + 4 * i + 2, wq.z);
        atomicAdd(wsv + 4 * i + 3, wq.w);
    }
}

extern "C" void kernel_launch(void* const* d_in, const int* in_sizes, int n_in,
                              void* d_out, int out_size, void* d_ws, size_t ws_size,
                              hipStream_t stream) {
    const float* X = (const float*)d_in[0];
    const float* C = (const float*)d_in[1];
    const float* W = (const float*)d_in[2];
    float* out = (float*)d_out;
    int n = in_sizes[0] / D_DIM;        // 500000
    int k_total = in_sizes[1] / D_DIM;  // 512

    int nsegmax = k_total + (n + SEGROWS - 1) / SEGROWS;
    int nblk = (n + 255) / 256;
    int ntiles = (n + RPT - 1) / RPT;
    int agrid = ntiles < AGRID_MAX ? ntiles : AGRID_MAX;

    char* ws = (char*)d_ws;
    int*            count   = (int*)ws;
    float*          inertia = (float*)(ws + 2048);
    int*            segmeta = (int*)(ws + 2056);
    float*          cchalf  = (float*)(ws + 2560);
    int*            offset  = (int*)(ws + 8192);
    unsigned short* Cb      = (unsigned short*)(ws + 12288); // 64 KB

    size_t base = 81920;
    size_t x16_bytes = (size_t)n * 128;                      // 64 MB bf16 rows
    size_t full_tab  = base + x16_bytes;
    size_t needed_full = full_tab + (size_t)n * 12 +
                         (size_t)AGRID_MAX * K_CLUS * 4 + (size_t)nsegmax * 4;

    hipMemsetAsync(ws, 0, 4096, stream);
    hipMemsetAsync(d_out, 0, (size_t)out_size * sizeof(float), stream);
    cc_kernel<<<(k_total + 255) / 256, 256, 0, stream>>>(C, cchalf, Cb, k_total);

    if (ws_size >= needed_full) {
        uint4* X16    = (uint4*)(ws + base);
        int* yv       = (int*)(ws + full_tab);
        int* lrank    = (int*)(ws + full_tab + (size_t)n * 4);
        int* sorted   = (int*)(ws + full_tab + (size_t)n * 8);
        int* baseTab  = (int*)(ws + full_tab + (size_t)n * 12);
        int* segKS    = (int*)(ws + full_tab + (size_t)n * 12 +
                               (size_t)AGRID_MAX * K_CLUS * 4);
        assign_mfma<<<agrid, 512, 0, stream>>>(X, Cb, cchalf, yv, lrank, baseTab,
                                               count, inertia, X16, n, ntiles);
        prefix_kernel<<<1, K_CLUS, 0, stream>>>(count, offset, segKS, segmeta);
        scatter_kernel<<<nblk, 256, 0, stream>>>(yv, lrank, offset, baseTab, sorted, n, agrid);
        cluster_accum_v3<<<nsegmax, 256, 0, stream>>>(X16, W, sorted, offset, count,
                                                      segKS, segmeta, out);
        finalize_kernel<<<1, D_DIM, 0, stream>>>(inertia, out);
    } else {
        int* yv = (int*)(ws + base);
        assign_scalar<<<nblk, 256, 0, stream>>>(X, C, cchalf, yv, count, inertia, n);
        accum_atomic_kernel<<<nblk, 256, 0, stream>>>(X, W, yv, out, n);
        finalize_kernel<<<1, D_DIM, 0, stream>>>(inertia, out);
    }
}

// Round 16
// 122.988 us; speedup vs baseline: 1.9420x; 1.0485x over previous
//
#include <hip/hip_runtime.h>
#include <hip/hip_bf16.h>

// N=500000, D=64, K=512 (fp32 in/out).
// out rows: [0,K)=xw_sum, [K,2K)=w_sum, row 2K = inertia broadcast to 64 cols.
// Champion hot kernels (130us structure) + launcher-only dispatch fusion.

#define D_DIM 64
#define K_CLUS 512
#define RPT 128           // X rows per tile in assign
#define AGRID_MAX 1024    // assign grid (4 blocks/CU)
#define SEGROWS 64        // rows per accumulation segment (balanced)

typedef __attribute__((ext_vector_type(8))) short short8;
typedef __attribute__((ext_vector_type(4))) float f32x4;

__device__ inline float dot4sq(float4 a) {
    return a.x * a.x + a.y * a.y + a.z * a.z + a.w * a.w;
}
__device__ inline unsigned short bfb(float f) {   // fp32 -> bf16 bits, RNE
    unsigned int u = __float_as_uint(f);
    return (unsigned short)((u + 0x7FFFu + ((u >> 16) & 1u)) >> 16);
}
__device__ inline short8 pack8f(float4 a, float4 b) {
    union { short8 s; __hip_bfloat162 q[4]; } r;
    r.q[0] = __float22bfloat162_rn(make_float2(a.x, a.y));
    r.q[1] = __float22bfloat162_rn(make_float2(a.z, a.w));
    r.q[2] = __float22bfloat162_rn(make_float2(b.x, b.y));
    r.q[3] = __float22bfloat162_rn(make_float2(b.z, b.w));
    return r.s;
}
__device__ inline float bfhi(unsigned u) { return __uint_as_float(u & 0xFFFF0000u); }
__device__ inline float bflo(unsigned u) { return __uint_as_float(u << 16); }

// -------- Kernel 1: cc + bf16 pack of C + (fused) zero ws page & d_out --------
// grid = 6 x 256: blocks 0,1 = cc; block 2 = zero ws[0,4096); blocks 3..5 = zero out.
// cchalf lives at ws+4608, OUTSIDE the zeroed page (no intra-kernel race).
__global__ __launch_bounds__(256) void cc_kernel(
        const float* __restrict__ C, float* __restrict__ CChalf,
        unsigned short* __restrict__ Cb, int k_total,
        int* __restrict__ wspage, float* __restrict__ out, int out_sz) {
    int b = blockIdx.x, tid = threadIdx.x;
    if (b < 2) {
        int k = b * 256 + tid;
        if (k >= k_total) return;
        const float4* cp = (const float4*)(C + (size_t)k * D_DIM);
        unsigned short* ob = Cb + (size_t)k * D_DIM;
        float s = 0.f;
#pragma unroll
        for (int i = 0; i < 16; ++i) {
            float4 c = cp[i];
            s += dot4sq(c);
            ob[4 * i + 0] = bfb(c.x); ob[4 * i + 1] = bfb(c.y);
            ob[4 * i + 2] = bfb(c.z); ob[4 * i + 3] = bfb(c.w);
        }
        CChalf[k] = 0.5f * s;
    } else if (b == 2) {
        int4 z = {0, 0, 0, 0};
        ((int4*)wspage)[tid] = z;                 // 256 x 16B = 4096 B
    } else {
        float4 z = {0.f, 0.f, 0.f, 0.f};
        float4* o4 = (float4*)out;
        int n4 = out_sz >> 2;
        for (int i = (b - 3) * 256 + tid; i < n4; i += 768) o4[i] = z;
    }
}

// ---------------- Kernel 2: MFMA assignment (champion, unchanged) ----------------
__global__ __launch_bounds__(512, 4) void assign_mfma(
        const float* __restrict__ X, const unsigned short* __restrict__ Cb,
        const float* __restrict__ CChalf, int* __restrict__ y,
        int* __restrict__ lrank, int* __restrict__ baseTab,
        int* __restrict__ count, float* __restrict__ inertia_ws,
        uint4* __restrict__ X16, int n, int ntiles) {
    __shared__ __align__(16) char xb_lds[RPT * 128];        // 16 KB bf16, swizzled
    __shared__ __align__(16) unsigned int partial[RPT][8];  // 4 KB keys
    __shared__ float xs_lds[2][RPT];                        // 1 KB ||x||^2, dbuf
    __shared__ int lhist[K_CLUS];                           // 2 KB local histogram

    int tid = threadIdx.x;
    lhist[tid] = 0;

    int lane = tid & 63, wid = tid >> 6;
    int c15 = lane & 15, g = lane >> 4;
    int wbase = wid * 64;

    short8 cf0[4], cf1[4];
    f32x4 nc[4];                           // acc init = -0.5||c||^2 per reg slot
#pragma unroll
    for (int ct = 0; ct < 4; ++ct) {
        const char* cp = (const char*)(Cb + (size_t)(wbase + ct * 16 + c15) * D_DIM);
        cf0[ct] = *(const short8*)(cp + (g << 4));          // k = 8g..8g+7
        cf1[ct] = *(const short8*)(cp + 64 + (g << 4));     // k = 32+8g..
#pragma unroll
        for (int r2 = 0; r2 < 4; ++r2)
            nc[ct][r2] = -CChalf[wbase + ct * 16 + (g << 2) + r2];
    }

    // staging: thread covers 32B of row srow (A) and row 64+srow (B)
    int srow = tid >> 3;
    int sb = (tid & 7) << 4;
    int sf = (tid & 7) << 3;
    unsigned swz = ((unsigned)(srow & 7)) << 4;   // (srow+64)&7 == srow&7

    float4 a0 = {0,0,0,0}, a1 = {0,0,0,0}, b0 = {0,0,0,0}, b1 = {0,0,0,0};
    int tile = blockIdx.x;
    if (tile < ntiles) {
        int rA = min(tile * RPT + srow, n - 1);
        int rB = min(tile * RPT + 64 + srow, n - 1);
        const float4* xa = (const float4*)(X + (size_t)rA * D_DIM + sf);
        const float4* xb = (const float4*)(X + (size_t)rB * D_DIM + sf);
        a0 = xa[0]; a1 = xa[1]; b0 = xb[0]; b1 = xb[1];
    }
    float iner = 0.f;
    int it = 0;

    for (; tile < ntiles; tile += gridDim.x, ++it) {
        int par = it & 1;
        int rA = min(tile * RPT + srow, n - 1);
        int rB = min(tile * RPT + 64 + srow, n - 1);
        short8 pA = pack8f(a0, a1);
        short8 pB = pack8f(b0, b1);
        *(short8*)(xb_lds + (srow << 7) + (sb ^ swz)) = pA;
        *(short8*)(xb_lds + ((64 + srow) << 7) + (sb ^ swz)) = pB;
        float psA = dot4sq(a0) + dot4sq(a1);
        float psB = dot4sq(b0) + dot4sq(b1);
        psA += __shfl_xor(psA, 1); psA += __shfl_xor(psA, 2); psA += __shfl_xor(psA, 4);
        psB += __shfl_xor(psB, 1); psB += __shfl_xor(psB, 2); psB += __shfl_xor(psB, 4);
        if ((tid & 7) == 0) {
            xs_lds[par][srow] = psA;
            xs_lds[par][64 + srow] = psB;
        }
        __syncthreads();                                   // stage visible

        // X16 stores AFTER the barrier: drain during the sweep
        union { short8 s8; uint4 u4; } cA, cB;
        cA.s8 = pA; cB.s8 = pB;
        X16[(size_t)rA * 8 + (tid & 7)] = cA.u4;
        X16[(size_t)rB * 8 + (tid & 7)] = cB.u4;

        // issue next tile's loads (latency hides under sweep)
        int ntile = tile + gridDim.x;
        if (ntile < ntiles) {
            int nA = min(ntile * RPT + srow, n - 1);
            int nB = min(ntile * RPT + 64 + srow, n - 1);
            const float4* xa = (const float4*)(X + (size_t)nA * D_DIM + sf);
            const float4* xb = (const float4*)(X + (size_t)nB * D_DIM + sf);
            a0 = xa[0]; a1 = xa[1]; b0 = xb[0]; b1 = xb[1];
        }

        // ---- sweep: 8 row-subtiles x wave's 64 clusters ----
#pragma unroll
        for (int s = 0; s < 8; ++s) {
            int arow = s * 16 + c15;                       // x-row (B col)
            const char* ab = xb_lds + (arow << 7);
            unsigned asw = ((unsigned)(arow & 7)) << 4;
            short8 xa = *(const short8*)(ab + ((g << 4) ^ asw));
            short8 xbv = *(const short8*)(ab + ((64 + (g << 4)) ^ asw));

            float best = -3.4e38f;
            int bpos = 0;
#pragma unroll
            for (int ct = 0; ct < 4; ++ct) {
                // chained acc: K-halves summed inside the MFMA pipe
                f32x4 acc = __builtin_amdgcn_mfma_f32_16x16x32_bf16(cf0[ct], xa, nc[ct], 0, 0, 0);
                acc = __builtin_amdgcn_mfma_f32_16x16x32_bf16(cf1[ct], xbv, acc, 0, 0, 0);
                float sc0 = acc[0], sc1 = acc[1], sc2 = acc[2], sc3 = acc[3];
                bool b01 = sc1 > sc0;  float v01 = b01 ? sc1 : sc0;  int p01 = b01 ? 1 : 0;
                bool b23 = sc3 > sc2;  float v23 = b23 ? sc3 : sc2;  int p23 = b23 ? 3 : 2;
                bool bq  = v23 > v01;  float vq  = bq ? v23 : v01;   int pq  = bq ? p23 : p01;
                if (vq > best) { best = vq; bpos = (ct << 2) + pq; }
            }
            int kg = wbase + ((bpos >> 2) << 4) + (g << 2) + (bpos & 3);
            unsigned u = __float_as_uint(best);
            unsigned mono = u ^ ((u & 0x80000000u) ? 0xFFFFFFFFu : 0x80000000u);
            unsigned key = (mono & 0xFFFFFE00u) | ((unsigned)kg ^ 0x1FFu);
            unsigned o = (unsigned)__shfl_xor((int)key, 16); key = key > o ? key : o;
            o = (unsigned)__shfl_xor((int)key, 32); key = key > o ? key : o;
            if (g == 0) partial[s * 16 + c15][wid] = key;
        }
        __syncthreads();                                   // partials visible

        // ---- merge: waves 0-1 only (tid<RPT); rank via LDS atomic ----
        if (tid < RPT) {
            int grow = tile * RPT + tid;
            if (grow < n) {
                const uint4* pp = (const uint4*)&partial[tid][0];
                uint4 p0 = pp[0], p1 = pp[1];
                unsigned key = p0.x;
                key = key > p0.y ? key : p0.y;
                key = key > p0.z ? key : p0.z;
                key = key > p0.w ? key : p0.w;
                key = key > p1.x ? key : p1.x;
                key = key > p1.y ? key : p1.y;
                key = key > p1.z ? key : p1.z;
                key = key > p1.w ? key : p1.w;
                int kg = (int)((key & 0x1FFu) ^ 0x1FFu);
                unsigned m2 = (key & 0xFFFFFE00u) | 0x100u;
                unsigned ub = (m2 & 0x80000000u) ? (m2 ^ 0x80000000u) : ~m2;
                float sbest = __uint_as_float(ub);
                float xx = xs_lds[par][tid];
                y[grow] = kg;
                lrank[grow] = atomicAdd(&lhist[kg], 1);
                iner += sqrtf(fmaxf(xx - 2.f * sbest, 0.f) * (1.0f / 64.0f));
            }
        }
    }

    __syncthreads();
    int b = atomicAdd(count + tid, lhist[tid]);
    baseTab[blockIdx.x * K_CLUS + tid] = b;

    if (wid < 2) {                        // waves 0,1 hold inertia partials
#pragma unroll
        for (int off = 1; off < 64; off <<= 1) iner += __shfl_xor(iner, off);
        if (lane == 0) atomicAdd(inertia_ws, iner);
    }
}

// ------- Kernel 3: prefix sums + segment worklist + (fused) inertia row -------
__global__ __launch_bounds__(K_CLUS) void prefix_kernel(
        const int* __restrict__ count, int* __restrict__ offset,
        int* __restrict__ segKS, int* __restrict__ segmeta,
        const float* __restrict__ inertia_ws, float* __restrict__ out) {
    __shared__ int tmp[K_CLUS];
    __shared__ int tns[K_CLUS];
    int t = threadIdx.x;
    int c = count[t];
    int ns = (c + SEGROWS - 1) / SEGROWS;
    tmp[t] = c; tns[t] = ns;
    __syncthreads();
    for (int s = 1; s < K_CLUS; s <<= 1) {
        int v1 = (t >= s) ? tmp[t - s] : 0;
        int v2 = (t >= s) ? tns[t - s] : 0;
        __syncthreads();
        tmp[t] += v1; tns[t] += v2;
        __syncthreads();
    }
    offset[t] = tmp[t] - c;                 // exclusive row offset
    int so = tns[t] - ns;                   // exclusive segment offset
    for (int s = 0; s < ns; ++s) segKS[so + s] = (t << 16) | s;
    if (t == K_CLUS - 1) segmeta[0] = tns[t];
    if (t < D_DIM) out[(size_t)(2 * K_CLUS) * D_DIM + t] = *inertia_ws;  // finalize
}

// ---------------- Kernel 4: scatter rows into cluster-sorted order ----------------
__global__ __launch_bounds__(256) void scatter_kernel(
        const int* __restrict__ y, const int* __restrict__ lrank,
        const int* __restrict__ offset, const int* __restrict__ baseTab,
        int* __restrict__ sorted, int n, int agrid) {
    int row = blockIdx.x * blockDim.x + threadIdx.x;
    if (row >= n) return;
    int k = y[row];
    int blk = (row / RPT) % agrid;    // tile -> assign block id (RPT rows/tile)
    sorted[offset[k] + baseTab[blk * K_CLUS + k] + lrank[row]] = row;
}

// ------- Kernel 5: compressed gather accumulation (champion, unchanged) -------
__global__ __launch_bounds__(256, 6) void cluster_accum_v3(
        const uint4* __restrict__ X16, const float* __restrict__ W,
        const int* __restrict__ sorted, const int* __restrict__ offset,
        const int* __restrict__ count, const int* __restrict__ segKS,
        const int* __restrict__ segmeta, float* __restrict__ out) {
    int bid = blockIdx.x;
    if (bid >= segmeta[0]) return;
    int v = segKS[bid];
    int k = v >> 16, s = v & 0xFFFF;
    int cnt = count[k];
    int lo = s * SEGROWS;
    int m = min(cnt - lo, SEGROWS);
    int start = offset[k] + lo;
    int lane = threadIdx.x & 63, w = threadIdx.x >> 6;
    int grp = (w << 2) | (lane >> 4);       // 0..15
    int l8 = lane & 7;                      // dim block: dims 8*l8..8*l8+7
    int h = (lane >> 3) & 1;                // row half
    int g4 = grp * 4;
    const float4* W4 = (const float4*)W;

    int i0 = g4 + h;
    int i1 = g4 + 2 + h;
    int r0 = (i0 < m) ? sorted[start + i0] : -1;
    int r1 = (i1 < m) ? sorted[start + i1] : -1;

    uint4 zz = {0u, 0u, 0u, 0u};
    float4 fz = {0.f, 0.f, 0.f, 0.f};
    uint4 xq0 = zz, xq1 = zz;
    float4 wa0 = fz, wb0 = fz, wa1 = fz, wb1 = fz;
    if (r0 >= 0) {
        xq0 = X16[(size_t)r0 * 8 + l8];
        wa0 = W4[(size_t)r0 * 16 + 2 * l8];
        wb0 = W4[(size_t)r0 * 16 + 2 * l8 + 1];
    }
    if (r1 >= 0) {
        xq1 = X16[(size_t)r1 * 8 + l8];
        wa1 = W4[(size_t)r1 * 16 + 2 * l8];
        wb1 = W4[(size_t)r1 * 16 + 2 * l8 + 1];
    }

    float axw[8], aww[8];
#pragma unroll
    for (int j = 0; j < 8; ++j) { axw[j] = 0.f; aww[j] = 0.f; }

#pragma unroll
    for (int r = 0; r < 2; ++r) {
        uint4 xq = r ? xq1 : xq0;
        float4 wa = r ? wa1 : wa0;
        float4 wb = r ? wb1 : wb0;
        float xf[8];
        xf[0] = bflo(xq.x); xf[1] = bfhi(xq.x);
        xf[2] = bflo(xq.y); xf[3] = bfhi(xq.y);
        xf[4] = bflo(xq.z); xf[5] = bfhi(xq.z);
        xf[6] = bflo(xq.w); xf[7] = bfhi(xq.w);
        axw[0] = fmaf(xf[0], wa.x, axw[0]); aww[0] += wa.x;
        axw[1] = fmaf(xf[1], wa.y, axw[1]); aww[1] += wa.y;
        axw[2] = fmaf(xf[2], wa.z, axw[2]); aww[2] += wa.z;
        axw[3] = fmaf(xf[3], wa.w, axw[3]); aww[3] += wa.w;
        axw[4] = fmaf(xf[4], wb.x, axw[4]); aww[4] += wb.x;
        axw[5] = fmaf(xf[5], wb.y, axw[5]); aww[5] += wb.y;
        axw[6] = fmaf(xf[6], wb.z, axw[6]); aww[6] += wb.z;
        axw[7] = fmaf(xf[7], wb.w, axw[7]); aww[7] += wb.w;
    }
#pragma unroll
    for (int j = 0; j < 8; ++j) {
        axw[j] += __shfl_xor(axw[j], 8);
        aww[j] += __shfl_xor(aww[j], 8);
    }

    __shared__ float sxw[16][D_DIM];
    __shared__ float sww[16][D_DIM];
    if (h == 0) {
#pragma unroll
        for (int j = 0; j < 8; ++j) {
            sxw[grp][8 * l8 + j] = axw[j];
            sww[grp][8 * l8 + j] = aww[j];
        }
    }
    __syncthreads();
    int t = threadIdx.x;
    if (t < 128) {
        int half = t >> 6, d = t & 63;
        const float(*src)[D_DIM] = half ? sww : sxw;
        float acc = 0.f;
#pragma unroll
        for (int jg = 0; jg < 16; ++jg) acc += src[jg][d];
        atomicAdd(out + (size_t)(half ? K_CLUS + k : k) * D_DIM + d, acc);
    }
}

// ---------------- Fallback-only kernels ----------------
__global__ void finalize_kernel(const float* __restrict__ inertia_ws, float* __restrict__ out) {
    out[(size_t)(2 * K_CLUS) * D_DIM + threadIdx.x] = *inertia_ws;
}

__global__ __launch_bounds__(256) void assign_scalar(
        const float* __restrict__ X, const float* __restrict__ C,
        const float* __restrict__ CChalf, int* __restrict__ y,
        int* __restrict__ count, float* __restrict__ inertia_ws, int n) {
    int row = blockIdx.x * blockDim.x + threadIdx.x;
    float mind = 0.f;
    if (row < n) {
        float4 x[16];
        const float4* xp = (const float4*)(X + (size_t)row * D_DIM);
#pragma unroll
        for (int i = 0; i < 16; ++i) x[i] = xp[i];
        float xx = 0.f;
#pragma unroll
        for (int i = 0; i < 16; ++i) xx += dot4sq(x[i]);
        float best = -3.4e38f;
        int bestk = 0;
        for (int k = 0; k < K_CLUS; ++k) {
            const float4* cp = (const float4*)(C + (size_t)k * D_DIM);
            float s0 = 0.f;
#pragma unroll
            for (int i = 0; i < 16; ++i) {
                float4 c = cp[i];
                s0 += x[i].x * c.x + x[i].y * c.y + x[i].z * c.z + x[i].w * c.w;
            }
            float sc = s0 - CChalf[k];
            if (sc > best) { best = sc; bestk = k; }
        }
        y[row] = bestk;
        atomicAdd(&count[bestk], 1);
        mind = sqrtf(fmaxf(xx - 2.f * best, 0.f) * (1.0f / 64.0f));
    }
    float s = mind;
#pragma unroll
    for (int off = 32; off > 0; off >>= 1) s += __shfl_xor(s, off);
    __shared__ float wsum[4];
    int w = threadIdx.x >> 6;
    if ((threadIdx.x & 63) == 0) wsum[w] = s;
    __syncthreads();
    if (threadIdx.x == 0)
        atomicAdd(inertia_ws, wsum[0] + wsum[1] + wsum[2] + wsum[3]);
}

__global__ __launch_bounds__(256) void accum_atomic_kernel(
        const float* __restrict__ X, const float* __restrict__ W,
        const int* __restrict__ y, float* __restrict__ out, int n) {
    int row = blockIdx.x * blockDim.x + threadIdx.x;
    if (row >= n) return;
    int k = y[row];
    const float4* xp = (const float4*)(X + (size_t)row * D_DIM);
    const float4* wp = (const float4*)(W + (size_t)row * D_DIM);
    float* xw = out + (size_t)k * D_DIM;
    float* wsv = out + (size_t)(K_CLUS + k) * D_DIM;
#pragma unroll
    for (int i = 0; i < 16; ++i) {
        float4 x = xp[i];
        float4 wq = wp[i];
        atomicAdd(xw + 4 * i + 0, x.x * wq.x);
        atomicAdd(xw + 4 * i + 1, x.y * wq.y);
        atomicAdd(xw + 4 * i + 2, x.z * wq.z);
        atomicAdd(xw + 4 * i + 3, x.w * wq.w);
        atomicAdd(wsv + 4 * i + 0, wq.x);
        atomicAdd(wsv + 4 * i + 1, wq.y);
        atomicAdd(wsv + 4 * i + 2, wq.z);
        atomicAdd(wsv + 4 * i + 3, wq.w);
    }
}

extern "C" void kernel_launch(void* const* d_in, const int* in_sizes, int n_in,
                              void* d_out, int out_size, void* d_ws, size_t ws_size,
                              hipStream_t stream) {
    const float* X = (const float*)d_in[0];
    const float* C = (const float*)d_in[1];
    const float* W = (const float*)d_in[2];
    float* out = (float*)d_out;
    int n = in_sizes[0] / D_DIM;        // 500000
    int k_total = in_sizes[1] / D_DIM;  // 512

    int nsegmax = k_total + (n + SEGROWS - 1) / SEGROWS;
    int nblk = (n + 255) / 256;
    int ntiles = (n + RPT - 1) / RPT;
    int agrid = ntiles < AGRID_MAX ? ntiles : AGRID_MAX;

    char* ws = (char*)d_ws;
    int*            count   = (int*)ws;                      // [0,2048)
    float*          inertia = (float*)(ws + 2048);
    int*            segmeta = (int*)(ws + 2056);
    float*          cchalf  = (float*)(ws + 4608);           // OUTSIDE zeroed page
    int*            offset  = (int*)(ws + 8192);
    unsigned short* Cb      = (unsigned short*)(ws + 12288); // 64 KB

    size_t base = 81920;
    size_t x16_bytes = (size_t)n * 128;                      // 64 MB bf16 rows
    size_t full_tab  = base + x16_bytes;
    size_t needed_full = full_tab + (size_t)n * 12 +
                         (size_t)AGRID_MAX * K_CLUS * 4 + (size_t)nsegmax * 4;

    if (ws_size >= needed_full) {
        uint4* X16    = (uint4*)(ws + base);
        int* yv       = (int*)(ws + full_tab);
        int* lrank    = (int*)(ws + full_tab + (size_t)n * 4);
        int* sorted   = (int*)(ws + full_tab + (size_t)n * 8);
        int* baseTab  = (int*)(ws + full_tab + (size_t)n * 12);
        int* segKS    = (int*)(ws + full_tab + (size_t)n * 12 +
                               (size_t)AGRID_MAX * K_CLUS * 4);

        cc_kernel<<<6, 256, 0, stream>>>(C, cchalf, Cb, k_total,
                                         (int*)ws, out, out_size);
        assign_mfma<<<agrid, 512, 0, stream>>>(X, Cb, cchalf, yv, lrank, baseTab,
                                               count, inertia, X16, n, ntiles);
        prefix_kernel<<<1, K_CLUS, 0, stream>>>(count, offset, segKS, segmeta,
                                                inertia, out);
        scatter_kernel<<<nblk, 256, 0, stream>>>(yv, lrank, offset, baseTab,
                                                 sorted, n, agrid);
        cluster_accum_v3<<<nsegmax, 256, 0, stream>>>(X16, W, sorted, offset, count,
                                                      segKS, segmeta, out);
    } else {
        int* yv = (int*)(ws + base);
        hipMemsetAsync(ws, 0, 4096, stream);
        hipMemsetAsync(d_out, 0, (size_t)out_size * sizeof(float), stream);
        cc_kernel<<<6, 256, 0, stream>>>(C, cchalf, Cb, k_total,
                                         (int*)ws, out, out_size);
        assign_scalar<<<nblk, 256, 0, stream>>>(X, C, cchalf, yv, count, inertia, n);
        accum_atomic_kernel<<<nblk, 256, 0, stream>>>(X, W, yv, out, n);
        finalize_kernel<<<1, D_DIM, 0, stream>>>(inertia, out);
    }
}